// Round 5
// baseline (157.171 us; speedup 1.0000x reference)
//
#include <hip/hip_runtime.h>

#define HID 20

typedef float v2f __attribute__((ext_vector_type(2)));

// Packed SiLU on two activations: pk_mul, 2x v_exp_f32, pk_add, 2x v_rcp_f32,
// pk_mul  -> 3 packed VALU + 4 trans ops per two outputs.
__device__ __forceinline__ v2f silu2(v2f a) {
    v2f m = a * (-1.442695040888963f);            // v_pk_mul_f32
    float e0 = __builtin_amdgcn_exp2f(m.x);
    float e1 = __builtin_amdgcn_exp2f(m.y);
    v2f d = (v2f){e0, e1} + 1.0f;                 // v_pk_add_f32
    v2f r = {__builtin_amdgcn_rcpf(d.x), __builtin_amdgcn_rcpf(d.y)};
    return a * r;                                  // v_pk_mul_f32
}

// 20->20 layer, K-packed: acc pair accumulates even/odd K partial sums of ONE
// output. Weight pairs {W[j][2i],W[j][2i+1]} are ADJACENT floats -> uniform
// s_load_dwordx2 -> direct SGPR-pair operand of v_pk_fma_f32 (no v_mov
// broadcast, unlike the R4 point-packed form). h stays as 10 natural v2f.
// Two rows (j, j+1) in flight for ILP; rows are 80 B apart -> 8/16B aligned.
__device__ __forceinline__ void layer20(const float* __restrict__ W,
                                        const float* __restrict__ b,
                                        const v2f* h, v2f* hn) {
    #pragma unroll
    for (int jp = 0; jp < HID / 2; ++jp) {
        const float* r0 = W + (2 * jp) * HID;
        const float* r1 = W + (2 * jp + 1) * HID;
        v2f acc0 = h[0] * *(const v2f*)(r0);
        v2f acc1 = h[0] * *(const v2f*)(r1);
        #pragma unroll
        for (int ip = 1; ip < HID / 2; ++ip) {
            acc0 = __builtin_elementwise_fma(h[ip], *(const v2f*)(r0 + 2 * ip), acc0);
            acc1 = __builtin_elementwise_fma(h[ip], *(const v2f*)(r1 + 2 * ip), acc1);
        }
        // horizontal finish: halves of a v2f are plain consecutive VGPRs,
        // so these are ordinary v_add_f32 (bias operand comes from SGPR).
        v2f a = { acc0.x + acc0.y + b[2 * jp],
                  acc1.x + acc1.y + b[2 * jp + 1] };
        hn[jp] = silu2(a);
    }
}

// Live set ~50 VGPRs (10 h-pairs + up to 10 hn-pairs + 2 acc-pairs + temps).
// (256,6): ~85-VGPR budget, 6 waves/SIMD floor -> better latency overlap than
// R4's 40% occupancy without risking spills at a 64-reg cap.
__global__ __launch_bounds__(256, 6) void SpringEquationNN_70102456205450_kernel(
    const float* __restrict__ t,
    const float* __restrict__ W0, const float* __restrict__ b0,
    const float* __restrict__ W1, const float* __restrict__ b1,
    const float* __restrict__ W2, const float* __restrict__ b2,
    const float* __restrict__ W3, const float* __restrict__ b3,
    const float* __restrict__ W4, const float* __restrict__ b4,
    const float* __restrict__ W5, const float* __restrict__ b5,
    const float* __restrict__ W6, const float* __restrict__ b6,
    const float* __restrict__ W7, const float* __restrict__ b7,
    float* __restrict__ out, int n)
{
    int idx = blockIdx.x * blockDim.x + threadIdx.x;
    if (idx >= n) return;

    float x = t[idx];

    v2f h[HID / 2], hn[HID / 2];

    // Layer 0: 1 -> 20. W0/b0 pairs are adjacent -> SGPR pairs; {x,x} is one
    // hoisted broadcast for all 10 pk_fma.
    v2f xx = {x, x};
    #pragma unroll
    for (int jp = 0; jp < HID / 2; ++jp) {
        v2f w = *(const v2f*)(W0 + 2 * jp);
        v2f bb = *(const v2f*)(b0 + 2 * jp);
        h[jp] = silu2(__builtin_elementwise_fma(xx, w, bb));
    }

    // Layers 1..6: 20 -> 20, SiLU
    layer20(W1, b1, h, hn);
    layer20(W2, b2, hn, h);
    layer20(W3, b3, h, hn);
    layer20(W4, b4, hn, h);
    layer20(W5, b5, h, hn);
    layer20(W6, b6, hn, h);

    // Layer 7: 20 -> 1 (no activation). W7 contiguous -> K-packed pairs.
    v2f acc = h[0] * *(const v2f*)(W7);
    #pragma unroll
    for (int ip = 1; ip < HID / 2; ++ip)
        acc = __builtin_elementwise_fma(h[ip], *(const v2f*)(W7 + 2 * ip), acc);

    out[idx] = acc.x + acc.y + b7[0];
}

extern "C" void kernel_launch(void* const* d_in, const int* in_sizes, int n_in,
                              void* d_out, int out_size, void* d_ws, size_t ws_size,
                              hipStream_t stream) {
    const float* t  = (const float*)d_in[0];
    const float* W0 = (const float*)d_in[1];
    const float* b0 = (const float*)d_in[2];
    const float* W1 = (const float*)d_in[3];
    const float* b1 = (const float*)d_in[4];
    const float* W2 = (const float*)d_in[5];
    const float* b2 = (const float*)d_in[6];
    const float* W3 = (const float*)d_in[7];
    const float* b3 = (const float*)d_in[8];
    const float* W4 = (const float*)d_in[9];
    const float* b4 = (const float*)d_in[10];
    const float* W5 = (const float*)d_in[11];
    const float* b5 = (const float*)d_in[12];
    const float* W6 = (const float*)d_in[13];
    const float* b6 = (const float*)d_in[14];
    const float* W7 = (const float*)d_in[15];
    const float* b7 = (const float*)d_in[16];
    float* out = (float*)d_out;

    int n = in_sizes[0];  // N points
    int block = 256;
    int grid = (n + block - 1) / block;
    SpringEquationNN_70102456205450_kernel<<<grid, block, 0, stream>>>(
        t, W0, b0, W1, b1, W2, b2, W3, b3, W4, b4, W5, b5, W6, b6, W7, b7,
        out, n);
}